// Round 5
// baseline (71.283 us; speedup 1.0000x reference)
//
#include <hip/hip_runtime.h>
#include <hip/hip_bf16.h>
#include <stdint.h>

// C[4096,10532] = inputs[4096,256] @ concat(lut,queue)[10532,256]^T  (fp32 out)
// R5: counted-vmcnt 2-phase pipeline (T3/T4 minimal recipe):
//   - BK=32, double-buffered LDS = 32 KB total -> 4-5 blocks/CU stay resident
//   - steady-state s_waitcnt vmcnt(4): next tile's loads stay in flight
//     across barriers; vmcnt(0) only on the last K-tile
//   - asm volatile s_barrier WITH "memory" clobber (R2 raced because the
//     IntrNoMem builtin let the next STAGE hoist above the barrier)
//   - BK=32 natural layout is LDS-bank-conflict-free (rows 64B apart), no swizzle
//   - regular cached C stores (NT amplified writes in R3)

#define M_DIM 4096
#define K_DIM 256
#define N_LUT 5532
#define N_Q   5000
#define N_DIM (N_LUT + N_Q)   // 10532
#define NT_M  32              // 4096/128
#define NT_N  83              // ceil(10532/128)
#define N_PAD (NT_N * 128)    // 10624

typedef _Float16 f16x8 __attribute__((ext_vector_type(8)));
typedef float f32x4 __attribute__((ext_vector_type(4)));

__device__ __forceinline__ unsigned short f2h(float f) {
  union { _Float16 h; unsigned short u; } v;
  v.h = (_Float16)f;   // v_cvt_f16_f32, RNE
  return v.u;
}

// ---------------- convert fp32 -> f16 into workspace ----------------
__global__ __launch_bounds__(256) void convert_kernel(
    const float* __restrict__ inp, const float* __restrict__ lut,
    const float* __restrict__ que, unsigned short* __restrict__ Abf,
    unsigned short* __restrict__ Bbf) {
  const int AV = M_DIM * K_DIM / 4;  // 262144 float4s for A
  int i = blockIdx.x * 256 + threadIdx.x;  // grid sized exactly
  float4 x;
  unsigned short* dst;
  if (i < AV) {
    x = ((const float4*)inp)[i];
    dst = Abf + i * 4;
  } else {
    int e = (i - AV) * 4;          // element index in padded B
    int row = e >> 8;              // /256
    int col = e & 255;
    if (row < N_LUT)
      x = *(const float4*)(lut + (size_t)row * K_DIM + col);
    else if (row < N_DIM)
      x = *(const float4*)(que + (size_t)(row - N_LUT) * K_DIM + col);
    else
      x = make_float4(0.f, 0.f, 0.f, 0.f);
    dst = Bbf + e;
  }
  ushort4 o;
  o.x = f2h(x.x); o.y = f2h(x.y); o.z = f2h(x.z); o.w = f2h(x.w);
  *(ushort4*)dst = o;
}

// ---------------- GEMM: C = A * B^T, both [rows][K] f16 ----------------
#define GLDS16(gsrc, ldst)                                                  \
  __builtin_amdgcn_global_load_lds(                                         \
      (__attribute__((address_space(1))) void*)(gsrc),                      \
      (__attribute__((address_space(3))) void*)(ldst), 16, 0, 0)

// compiler-level memory fence + hardware barrier (orders gload_lds/ds ops)
#define PIPE_BARRIER() asm volatile("s_barrier" ::: "memory")

__global__ __launch_bounds__(256, 4) void gemm_kernel(
    const unsigned short* __restrict__ A, const unsigned short* __restrict__ B,
    float* __restrict__ C) {
  // double-buffered 128x32 f16 tiles: 4 * 8 KB = 32 KB -> 5 blocks/CU (LDS)
  __shared__ __align__(16) unsigned short As[2][128 * 32];
  __shared__ __align__(16) unsigned short Bs[2][128 * 32];

  const int t = threadIdx.x;
  const int lane = t & 63;
  const int wave = t >> 6;         // 4 waves
  const int wm = wave >> 1;        // 2x2 wave grid, each 64x64 output
  const int wn = wave & 1;

  // XCD-aware swizzle: nwg = 32*83 = 2656, divisible by 8
  const int nwg = NT_M * NT_N;
  const int cpx = nwg >> 3;        // 332
  int bid = blockIdx.x;
  int wg = (bid & 7) * cpx + (bid >> 3);
  const int bm = wg & 31;          // m-fast: consecutive wg share B panel
  const int bn = wg >> 5;
  const int brow = bm * 128;
  const int bcol = bn * 128;

  // staging geometry (per 8 KB tile = 128 rows x 64 B):
  //   thread t covers bytes [is*4096 + t*16): row = is*64 + (t>>2),
  //   16B chunk = t&3.  LDS dest is wave-uniform base + lane*16 (linear).
  const int trow = t >> 2;                  // 0..63
  const unsigned short* gaBase = A + (size_t)(brow + trow) * K_DIM + (t & 3) * 8;
  const unsigned short* gbBase = B + (size_t)(bcol + trow) * K_DIM + (t & 3) * 8;
  const int ldsOff = wave * 512;            // elements (= wave*1024 B)

// 4 gload_lds per thread per STAGE (2 for A + 2 for B)
#define STAGE(buf, kt)                                                       \
  do {                                                                       \
    _Pragma("unroll") for (int is = 0; is < 2; ++is) {                       \
      GLDS16(gaBase + (size_t)is * 64 * K_DIM + (kt) * 32,                   \
             As[buf] + is * 2048 + ldsOff);                                  \
      GLDS16(gbBase + (size_t)is * 64 * K_DIM + (kt) * 32,                   \
             Bs[buf] + is * 2048 + ldsOff);                                  \
    }                                                                        \
  } while (0)

  f32x4 acc[4][4] = {};
  const int lr = lane & 15;
  const int kg = (lane >> 4) * 8;  // lane's 8 contiguous k-elems within BK=32

  STAGE(0, 0);                     // prologue: 4 loads in flight

#pragma unroll
  for (int kt = 0; kt < 8; ++kt) { // K = 256 = 8 * 32
    const int cur = kt & 1;
    if (kt < 7) {
      STAGE(cur ^ 1, kt + 1);      // 8 outstanding now
      // wait only for CURRENT tile's 4 loads; next tile's stay in flight
      asm volatile("s_waitcnt vmcnt(4)" ::: "memory");
    } else {
      asm volatile("s_waitcnt vmcnt(0)" ::: "memory");
    }
    PIPE_BARRIER();                        // tile[cur] resident for all waves
    __builtin_amdgcn_sched_barrier(0);     // no ds_read hoisting above

    f16x8 a[4], b[4];
#pragma unroll
    for (int i = 0; i < 4; ++i)
      a[i] = *(const f16x8*)&As[cur][(wm * 64 + i * 16 + lr) * 32 + kg];
#pragma unroll
    for (int j = 0; j < 4; ++j)
      b[j] = *(const f16x8*)&Bs[cur][(wn * 64 + j * 16 + lr) * 32 + kg];
#pragma unroll
    for (int i = 0; i < 4; ++i)
#pragma unroll
      for (int j = 0; j < 4; ++j)
        acc[i][j] = __builtin_amdgcn_mfma_f32_16x16x32_f16(a[i], b[j],
                                                           acc[i][j], 0, 0, 0);
    if (kt < 7) {
      // lgkmcnt(0) was drained before the MFMAs (compiler-enforced dep),
      // so all reads of buf[cur] are complete here. Barrier makes that true
      // for ALL waves before iteration kt+1 overwrites buf[cur].
      __builtin_amdgcn_sched_barrier(0);
      PIPE_BARRIER();
      __builtin_amdgcn_sched_barrier(0);
    }
  }

  // epilogue: C/D layout col = lane&15, row = (lane>>4)*4 + reg  [m89-verified]
  const int r0 = (lane >> 4) * 4;
#pragma unroll
  for (int j = 0; j < 4; ++j) {
    int col = bcol + wn * 64 + j * 16 + lr;
    if (col >= N_DIM) continue;   // N-boundary (last block covers 36 cols)
#pragma unroll
    for (int i = 0; i < 4; ++i) {
      size_t base = (size_t)(brow + wm * 64 + i * 16 + r0) * N_DIM + col;
#pragma unroll
      for (int r = 0; r < 4; ++r)
        C[base + (size_t)r * N_DIM] = acc[i][j][r];
    }
  }
#undef STAGE
}

extern "C" void kernel_launch(void* const* d_in, const int* in_sizes, int n_in,
                              void* d_out, int out_size, void* d_ws, size_t ws_size,
                              hipStream_t stream) {
  const float* inp = (const float*)d_in[0];   // inputs [4096,256]
  // d_in[1] targets, d_in[2] gt_flag: unused by the forward similarity
  const float* lut = (const float*)d_in[3];   // [5532,256]
  const float* que = (const float*)d_in[4];   // [5000,256]
  float* C = (float*)d_out;                   // [4096,10532]

  unsigned short* Abf = (unsigned short*)d_ws;
  unsigned short* Bbf = Abf + (size_t)M_DIM * K_DIM;  // ~7.6 MB of ws

  const int conv_blocks = (M_DIM * K_DIM / 4 + N_PAD * K_DIM / 4) / 256;
  convert_kernel<<<conv_blocks, 256, 0, stream>>>(inp, lut, que, Abf, Bbf);

  gemm_kernel<<<NT_M * NT_N, 256, 0, stream>>>(Abf, Bbf, C);
}

// Round 6
// 65.553 us; speedup vs baseline: 1.0874x; 1.0874x over previous
//
#include <hip/hip_runtime.h>
#include <hip/hip_bf16.h>
#include <stdint.h>

// C[4096,10532] = inputs[4096,256] @ concat(lut,queue)[10532,256]^T  (fp32 out)
// R6 = R4 base (single-buffer, __syncthreads, swizzled staging) plus:
//   - bn-FAST block order within each XCD chunk (332 = 4*83 exact): col-neighbor
//     blocks run concurrently on the same XCD -> their C-row edge lines merge
//     in L2 -> full-line HBM writes (kills partial-line ECC-RMW amplification).
//   - swapped-operand MFMA acc=mfma(b,a): lane holds 4 consecutive C-cols ->
//     dwordx4 C stores (16 instrs vs 64), tighter temporal line coverage.

#define M_DIM 4096
#define K_DIM 256
#define N_LUT 5532
#define N_Q   5000
#define N_DIM (N_LUT + N_Q)   // 10532
#define NT_M  32              // 4096/128
#define NT_N  83              // ceil(10532/128)
#define N_PAD (NT_N * 128)    // 10624

typedef _Float16 f16x8 __attribute__((ext_vector_type(8)));
typedef float f32x4 __attribute__((ext_vector_type(4)));

__device__ __forceinline__ unsigned short f2h(float f) {
  union { _Float16 h; unsigned short u; } v;
  v.h = (_Float16)f;   // v_cvt_f16_f32, RNE
  return v.u;
}

// ---------------- convert fp32 -> f16 into workspace ----------------
__global__ __launch_bounds__(256) void convert_kernel(
    const float* __restrict__ inp, const float* __restrict__ lut,
    const float* __restrict__ que, unsigned short* __restrict__ Abf,
    unsigned short* __restrict__ Bbf) {
  const int AV = M_DIM * K_DIM / 4;  // 262144 float4s for A
  int i = blockIdx.x * 256 + threadIdx.x;  // grid sized exactly
  float4 x;
  unsigned short* dst;
  if (i < AV) {
    x = ((const float4*)inp)[i];
    dst = Abf + i * 4;
  } else {
    int e = (i - AV) * 4;          // element index in padded B
    int row = e >> 8;              // /256
    int col = e & 255;
    if (row < N_LUT)
      x = *(const float4*)(lut + (size_t)row * K_DIM + col);
    else if (row < N_DIM)
      x = *(const float4*)(que + (size_t)(row - N_LUT) * K_DIM + col);
    else
      x = make_float4(0.f, 0.f, 0.f, 0.f);
    dst = Bbf + e;
  }
  ushort4 o;
  o.x = f2h(x.x); o.y = f2h(x.y); o.z = f2h(x.z); o.w = f2h(x.w);
  *(ushort4*)dst = o;
}

// ---------------- GEMM: C = A * B^T, both [rows][K] f16 ----------------
#define GLDS16(gsrc, ldst)                                                  \
  __builtin_amdgcn_global_load_lds(                                         \
      (__attribute__((address_space(1))) void*)(gsrc),                      \
      (__attribute__((address_space(3))) void*)(ldst), 16, 0, 0)

__global__ __launch_bounds__(256, 2) void gemm_kernel(
    const unsigned short* __restrict__ A, const unsigned short* __restrict__ B,
    float* __restrict__ C) {
  // single-buffered 128x64 f16 tiles: 32 KB total -> 5 blocks/CU resident
  __shared__ __align__(16) unsigned short As[128 * 64];
  __shared__ __align__(16) unsigned short Bs[128 * 64];

  const int t = threadIdx.x;
  const int lane = t & 63;
  const int wave = t >> 6;         // 4 waves
  const int wm = wave >> 1;        // 2x2 wave grid, each 64x64 output
  const int wn = wave & 1;

  // XCD chunking (nwg = 2656 = 8 * 332), then bn-FAST within each chunk:
  // 332 = 4*83, so each XCD owns bm in {4x..4x+3} across ALL bn. Consecutive
  // wg on an XCD are col-neighbors writing the SAME C rows -> L2 write-merge.
  const int nwg = NT_M * NT_N;
  const int cpx = nwg >> 3;        // 332
  int bid = blockIdx.x;
  int wg = (bid & 7) * cpx + (bid >> 3);
  const int bn = wg % NT_N;        // col-fast
  const int bm = wg / NT_N;
  const int brow = bm * 128;
  const int bcol = bn * 128;

  // ---- staging with PRE-SWIZZLED global source (LDS dest stays linear) ----
  // lds[row][ch] = global[row][ch ^ (row&7)]  (16B chunks), so thread t
  // (linear slot row = is*32 + (t>>3), chunk = t&7) fetches chunk^(row&7).
  const int trow = t >> 3;                       // 0..31
  const int tcs = (((t & 7) ^ (trow & 7)) * 8);  // swizzled col, elements
  const unsigned short* gaBase = A + (size_t)(brow + trow) * K_DIM + tcs;
  const unsigned short* gbBase = B + (size_t)(bcol + trow) * K_DIM + tcs;
  const int ldsOff = wave * 512;   // elements; HW adds lane*16 bytes

#define STAGE(kt)                                                            \
  do {                                                                       \
    _Pragma("unroll") for (int is = 0; is < 4; ++is) {                       \
      GLDS16(gaBase + (size_t)is * 32 * K_DIM + (kt) * 64,                   \
             As + is * 2048 + ldsOff);                                       \
      GLDS16(gbBase + (size_t)is * 32 * K_DIM + (kt) * 64,                   \
             Bs + is * 2048 + ldsOff);                                       \
    }                                                                        \
  } while (0)

  f32x4 acc[4][4] = {};
  const int lr = lane & 15;
  const int rsw = lane & 7;        // = row&7 for all fragment rows
  const int cq = lane >> 4;        // quarter-wave id = base col chunk

#pragma unroll
  for (int kt = 0; kt < 4; ++kt) { // K = 256 = 4 * 64
    STAGE(kt);
    __syncthreads();               // vmcnt(0)+lgkmcnt(0) drain + barrier

#pragma unroll
    for (int kk = 0; kk < 64; kk += 32) {
      // desired 16B chunk c = kk/8 + cq; read swizzled chunk c ^ (row&7)
      const int ch = ((kk >> 3) + cq) ^ rsw;   // 0..7
      f16x8 a[4], b[4];
#pragma unroll
      for (int i = 0; i < 4; ++i)
        a[i] = *(const f16x8*)&As[(wm * 64 + i * 16 + lr) * 64 + ch * 8];
#pragma unroll
      for (int j = 0; j < 4; ++j)
        b[j] = *(const f16x8*)&Bs[(wn * 64 + j * 16 + lr) * 64 + ch * 8];
      // SWAPPED operands: acc[i][j] = B_frag * A_frag => per lane:
      //   C-row = i*16 + (lane&15),  C-cols = j*16 + (lane>>4)*4 + reg[0..3]
#pragma unroll
      for (int i = 0; i < 4; ++i)
#pragma unroll
        for (int j = 0; j < 4; ++j)
          acc[i][j] = __builtin_amdgcn_mfma_f32_16x16x32_f16(b[j], a[i],
                                                             acc[i][j], 0, 0, 0);
    }
    __syncthreads();               // all waves done reading before next STAGE
  }

  // epilogue: lane holds 4 CONSECUTIVE cols -> dwordx4 stores.
  //   row = brow + wm*64 + i*16 + (lane&15)
  //   col = bcol + wn*64 + j*16 + (lane>>4)*4   (16B-aligned; N_DIM%4==0 so
  //   each 4-col granule is fully valid or fully invalid at the N boundary)
  const int cc4 = cq * 4;
#pragma unroll
  for (int i = 0; i < 4; ++i) {
    size_t rowBase = (size_t)(brow + wm * 64 + i * 16 + lr) * N_DIM;
#pragma unroll
    for (int j = 0; j < 4; ++j) {
      int col = bcol + wn * 64 + j * 16 + cc4;
      if (col < N_DIM)
        *(f32x4*)&C[rowBase + col] = acc[i][j];
    }
  }
#undef STAGE
}

extern "C" void kernel_launch(void* const* d_in, const int* in_sizes, int n_in,
                              void* d_out, int out_size, void* d_ws, size_t ws_size,
                              hipStream_t stream) {
  const float* inp = (const float*)d_in[0];   // inputs [4096,256]
  // d_in[1] targets, d_in[2] gt_flag: unused by the forward similarity
  const float* lut = (const float*)d_in[3];   // [5532,256]
  const float* que = (const float*)d_in[4];   // [5000,256]
  float* C = (float*)d_out;                   // [4096,10532]

  unsigned short* Abf = (unsigned short*)d_ws;
  unsigned short* Bbf = Abf + (size_t)M_DIM * K_DIM;  // ~7.6 MB of ws

  const int conv_blocks = (M_DIM * K_DIM / 4 + N_PAD * K_DIM / 4) / 256;
  convert_kernel<<<conv_blocks, 256, 0, stream>>>(inp, lut, que, Abf, Bbf);

  gemm_kernel<<<NT_M * NT_N, 256, 0, stream>>>(Abf, Bbf, C);
}